// Round 5
// baseline (926.082 us; speedup 1.0000x reference)
//
#include <hip/hip_runtime.h>
#include <hip/hip_bf16.h>
#include <cmath>

// Problem constants (from reference setup_inputs)
constexpr int Bdim = 64;
constexpr int Fdim = 4096;
constexpr int Edim = 256;
constexpr int Hdim = 512;
constexpr int Udim = 512;

typedef __attribute__((ext_vector_type(8))) short short8;   // 8 bf16 (16B)
typedef __attribute__((ext_vector_type(4))) float f32x4;

// ---------------------------------------------------------------------------
// Helpers
// ---------------------------------------------------------------------------
__device__ __forceinline__ unsigned short f2bf(float f) {
    unsigned int u = __float_as_uint(f);
    u += 0x7FFFu + ((u >> 16) & 1u);   // RNE; inputs finite
    return (unsigned short)(u >> 16);
}
// native RNE pair-convert: compiler emits v_cvt_pk_bf16_f32 (identical bits
// to the manual twiddle, ~1 op instead of ~7)
__device__ __forceinline__ unsigned int pack2(float lo, float hi) {
    __hip_bfloat162 h2 = __float22bfloat162_rn(make_float2(lo, hi));
    return *reinterpret_cast<unsigned int*>(&h2);
}
__device__ __forceinline__ float tanh_fast(float x) {
    float e = __expf(2.0f * x);
    return 1.0f - 2.0f * __builtin_amdgcn_rcpf(e + 1.0f);
}
// async global->LDS, 16B per lane; lds dest is wave-uniform base + lane*16
__device__ __forceinline__ void gload_lds16(const void* g, void* l) {
    __builtin_amdgcn_global_load_lds(
        (const __attribute__((address_space(1))) unsigned int*)g,
        (__attribute__((address_space(3))) unsigned int*)l, 16, 0, 0);
}

// ---------------------------------------------------------------------------
// Kernel 1 (fused prep): blocks 0..127   : cb[b][u] = W1b[u]+W2b[u]+hidden.W2
//                        blocks 128..159 : W1 -> transposed/swizzled bf16 W1Ts
//                        blocks 160..175 : zero ctx (needed by fallback path)
// ---------------------------------------------------------------------------
__global__ __launch_bounds__(256) void prep_kernel(
    const float* __restrict__ hidden, const float* __restrict__ W2,
    const float* __restrict__ W1b, const float* __restrict__ W2b,
    float* __restrict__ cb,
    const float* __restrict__ W1, unsigned short* __restrict__ Th,
    float* __restrict__ ctx, const int do_t)
{
    const int bid = blockIdx.x;
    const int tid = threadIdx.x;

    if (bid < 128) {
        // ---- proj_h ----
        const int b = bid >> 1;
        const int u = (bid & 1) * 256 + tid;
        const float* hb = hidden + (size_t)b * Hdim;
        float acc = 0.f;
        #pragma unroll 8
        for (int h = 0; h < Hdim; ++h)
            acc = fmaf(hb[h], W2[(size_t)h * Udim + u], acc);
        cb[(size_t)b * Udim + u] = acc + W1b[u] + W2b[u];
    } else if (bid < 160) {
        // ---- w1t: W1 (E,U) fp32 -> bf16 [U][E] with 16B-chunk XOR swizzle
        if (!do_t) return;
        __shared__ unsigned short sT[64][72];
        const int k  = bid - 128;            // 0..31 : (4 e-tiles) x (8 u-tiles)
        const int e0 = (k & 3) * 64, u0 = (k >> 2) * 64;
        const int ue = tid & 63, er = tid >> 6;
        #pragma unroll
        for (int it = 0; it < 16; ++it) {
            const int e = er + it * 4;
            sT[ue][e] = f2bf(W1[(size_t)(e0 + e) * Udim + u0 + ue]);
        }
        __syncthreads();
        const int ur = tid >> 2, cq = tid & 3;
        const int u = u0 + ur, s = u & 7;
        const int cA = (e0 >> 3) + cq * 2;   // global 16B-chunk index
        uint4 a  = *(const uint4*)&sT[ur][cq * 16];
        uint4 b2 = *(const uint4*)&sT[ur][cq * 16 + 8];
        unsigned short* dst = Th + (size_t)u * Edim;
        *(uint4*)(dst + ((cA ^ s) << 3))       = a;
        *(uint4*)(dst + (((cA + 1) ^ s) << 3)) = b2;
    } else {
        // ---- zero ctx ----
        const int idx = (bid - 160) * 256 + tid;
        ((float4*)ctx)[idx] = make_float4(0.f, 0.f, 0.f, 0.f);
    }
}

// ---------------------------------------------------------------------------
// Kernel 2 (dominant, flash-style, de-lockstepped):
// 2-wave blocks (128 thr), 64 f-rows/block, 8 blocks/CU (LDS 16,384 B,
// VGPR<=128 via launch_bounds). Per block:
//   Phase A: A-frags loaded DIRECTLY global->reg (per-lane 2xfloat4, no LDS,
//            no barrier), packed to bf16 via native cvt_pk.
//   32 u-windows of 16 rows (8 KB, double-buffered via global_load_lds):
//     8 ds_read_b128 -> 16 MFMA -> 8 tanh+V-dot; ONE 2-wave barrier/window.
//   Epilogue: block softmax stats (64 rows = 1/lane, pure shfl) + partial
//   context from L2-hot features. No second global features sweep.
// 8 phase-staggered blocks/CU overlap HBM / MFMA / LDS / VALU pipes that the
// previous 4-block-lockstep structure paid for additively.
// ---------------------------------------------------------------------------
__global__ __launch_bounds__(128, 4) void score_mfma4_kernel(
    const float* __restrict__ feat,            // [B][F][E] fp32
    const unsigned short* __restrict__ W1Ts,   // [U][E] bf16, chunk-swizzled
    const float* __restrict__ Vw, const float* __restrict__ Vb,
    const float* __restrict__ cb, float* __restrict__ scr,
    float* __restrict__ pm, float* __restrict__ ps, float* __restrict__ pc)
{
    __shared__ unsigned short lds[8192];   // 16,384 B: B dbuf / epilogue scratch

    const int b    = blockIdx.y;
    const int fc   = blockIdx.x;        // 0..63
    const int f0   = fc * 64;
    const int tid  = threadIdx.x;       // 0..127
    const int lane = tid & 63;
    const int w    = tid >> 6;          // wave id (0..1); 32 f-rows each
    const int ln15 = lane & 15;
    const int kq   = lane >> 4;         // 0..3
    const int swz  = ln15 & 7;

    // ---- stage u-window 0 (16 rows x 512 B = 8 KB) into buf0 ----
    #pragma unroll
    for (int t = 0; t < 4; ++t)
        gload_lds16((const char*)W1Ts + (size_t)(tid + t * 128) * 16,
                    (char*)lds + (tid + t * 128) * 16);

    // ---- Phase A: direct global->reg A-frags (row ln15, cols k8*32+kq*8) ----
    short8 af[2][8];
    {
        const float* gA = feat +
            ((size_t)(b * Fdim + f0 + w * 32 + ln15)) * Edim + kq * 8;
        #pragma unroll
        for (int h = 0; h < 2; ++h) {
            #pragma unroll 4
            for (int k8 = 0; k8 < 8; ++k8) {
                const float* p = gA + (size_t)h * 16 * Edim + k8 * 32;
                const float4 v0 = *(const float4*)(p);
                const float4 v1 = *(const float4*)(p + 4);
                uint4 uu;
                uu.x = pack2(v0.x, v0.y);
                uu.y = pack2(v0.z, v0.w);
                uu.z = pack2(v1.x, v1.y);
                uu.w = pack2(v1.z, v1.w);
                af[h][k8] = *reinterpret_cast<short8*>(&uu);
            }
        }
    }
    __syncthreads();   // window-0 staged; A-frags in regs

    float sacc[2][4] = {};   // [mi][r]
    const float* cbB = cb + (size_t)b * Udim;

    for (int p = 0; p < 32; ++p) {
        // issue-early prefetch of next window into the other buffer
        if (p < 31) {
            const char* gB = (const char*)(W1Ts + (size_t)(p + 1) * 16 * Edim);
            char* lb = (char*)lds + ((p + 1) & 1) * 8192;
            #pragma unroll
            for (int t = 0; t < 4; ++t)
                gload_lds16(gB + (size_t)(tid + t * 128) * 16,
                            lb + (tid + t * 128) * 16);
        }

        const unsigned short* bw = lds + (p & 1) * 4096;   // current window
        const int ub = p * 16;
        const float cu0 = cbB[ub + ln15];
        const float vv0 = Vw[ub + ln15];
        f32x4 acc0 = {}, acc1 = {};
        #pragma unroll
        for (int k8 = 0; k8 < 8; ++k8) {
            const int co = ((k8 * 4 + kq) ^ swz) * 8;   // swizzled chunk
            short8 b0 = *(const short8*)&bw[ln15 * 256 + co];
            acc0 = __builtin_amdgcn_mfma_f32_16x16x32_bf16(af[0][k8], b0, acc0, 0, 0, 0);
            acc1 = __builtin_amdgcn_mfma_f32_16x16x32_bf16(af[1][k8], b0, acc1, 0, 0, 0);
        }
        // fused epilogue: tanh + V-dot into running per-f partials
        #pragma unroll
        for (int r = 0; r < 4; ++r) {
            sacc[0][r] += tanh_fast(acc0[r] + cu0) * vv0;
            sacc[1][r] += tanh_fast(acc1[r] + cu0) * vv0;
        }

        if (p < 31) __syncthreads();   // reads done before buf reuse; drains
    }                                  // prefetch (covered by compute above)

    // ---- Phase B: scores -> LDS + global; block softmax stats ----
    // LDS overlay: sF/wl in bytes 0..511 (buf0), sred at 512..2559; window 31
    // reads buf1 (bytes 8192+) only, so no hazard.
    float* sF = (float*)lds;                       // 64 scores
    float* wl = (float*)lds + 64;                  // 64 weights
    float4* sred = (float4*)((char*)lds + 512);    // 128 float4

    const float vb = Vb[0];
    #pragma unroll
    for (int mi = 0; mi < 2; ++mi)
        #pragma unroll
        for (int r = 0; r < 4; ++r) {
            float s = sacc[mi][r];
            s += __shfl_xor(s, 1);
            s += __shfl_xor(s, 2);
            s += __shfl_xor(s, 4);
            s += __shfl_xor(s, 8);
            if (ln15 == 0) {
                const int fr = w * 32 + mi * 16 + kq * 4 + r;
                const float sv = s + vb;
                scr[(size_t)b * Fdim + f0 + fr] = sv;
                sF[fr] = sv;
            }
        }
    __syncthreads();

    if (tid < 64) {   // one wave: 64 rows = 1 score per lane, pure shfl
        const float sc_ = sF[tid];
        float m = sc_;
        #pragma unroll
        for (int off = 1; off < 64; off <<= 1)
            m = fmaxf(m, __shfl_xor(m, off));
        const float wv = expf(sc_ - m);
        float sm = wv;
        #pragma unroll
        for (int off = 1; off < 64; off <<= 1)
            sm += __shfl_xor(sm, off);
        wl[tid] = wv;
        if (tid == 0) {
            pm[b * 64 + fc] = m;
            ps[b * 64 + fc] = sm;
        }
    }
    __syncthreads();

    // ---- Phase C: partial context from L2-hot features (64 rows) ----
    // wave w accumulates rows w*32..w*32+31; lane owns float4-column `lane`
    const float4* fp = (const float4*)(feat + ((size_t)b * Fdim + f0) * Edim);
    float4 a = make_float4(0.f, 0.f, 0.f, 0.f);
    #pragma unroll 8
    for (int i = 0; i < 32; ++i) {
        const int f = w * 32 + i;
        const float4 fv = fp[(size_t)f * 64 + lane];
        const float wv = wl[f];
        a.x = fmaf(wv, fv.x, a.x);
        a.y = fmaf(wv, fv.y, a.y);
        a.z = fmaf(wv, fv.z, a.z);
        a.w = fmaf(wv, fv.w, a.w);
    }
    sred[tid] = a;
    __syncthreads();

    if (w == 0) {
        const float4 r0 = sred[lane];
        const float4 r1 = sred[64 + lane];
        float4 o;
        o.x = r0.x + r1.x;
        o.y = r0.y + r1.y;
        o.z = r0.z + r1.z;
        o.w = r0.w + r1.w;
        *(float4*)&pc[((size_t)b * 64 + fc) * 256 + lane * 4] = o;
    }
}

// ---------------------------------------------------------------------------
// Kernel 3: merge 64 partials per b (online-softmax combine), write ctx and
// normalized weights. 64 blocks; ~82 KB traffic each.
// ---------------------------------------------------------------------------
__global__ __launch_bounds__(256) void merge_kernel(
    const float* __restrict__ scr, const float* __restrict__ pm,
    const float* __restrict__ ps, const float* __restrict__ pc,
    float* __restrict__ wts, float* __restrict__ ctx)
{
    __shared__ float sscale[64];
    __shared__ float sms[2];

    const int b   = blockIdx.x;
    const int tid = threadIdx.x;

    if (tid < 64) {
        const float mi = pm[b * 64 + tid];
        float m = mi;
        #pragma unroll
        for (int off = 1; off < 64; off <<= 1)
            m = fmaxf(m, __shfl_xor(m, off));
        const float sc = expf(mi - m);
        float s = ps[b * 64 + tid] * sc;
        #pragma unroll
        for (int off = 1; off < 64; off <<= 1)
            s += __shfl_xor(s, off);
        sscale[tid] = sc;
        if (tid == 0) { sms[0] = m; sms[1] = 1.0f / s; }
    }
    __syncthreads();
    const float m   = sms[0];
    const float inv = sms[1];

    // context: thread t owns e = t
    {
        float c = 0.f;
        const float* p = pc + (size_t)b * 64 * 256 + tid;
        #pragma unroll 8
        for (int i = 0; i < 64; ++i)
            c = fmaf(p[(size_t)i * 256], sscale[i], c);
        ctx[(size_t)b * Edim + tid] = c * inv;
    }

    // normalized weights from raw scores
    const float* row  = scr + (size_t)b * Fdim;
    float*       wrow = wts + (size_t)b * Fdim;
    #pragma unroll
    for (int i = 0; i < 16; ++i) {
        const float v = row[tid + 256 * i];
        wrow[tid + 256 * i] = expf(v - m) * inv;
    }
}

// ---------------------------------------------------------------------------
// Fallback path (ws too small): fp32 score -> in-place softmax -> context
// ---------------------------------------------------------------------------
constexpr int TFt = 64;
constexpr int TUt = 64;
constexpr int LDR = Edim + 4;

__global__ __launch_bounds__(256) void score_kernel(
    const float* __restrict__ feat, const float* __restrict__ W1,
    const float* __restrict__ Vw, const float* __restrict__ Vb,
    const float* __restrict__ cb, float* __restrict__ scores)
{
    __shared__ float sA[TFt * LDR];
    __shared__ float sW[TUt * LDR];

    const int b   = blockIdx.y;
    const int f0  = blockIdx.x * TFt;
    const int tid = threadIdx.x;
    const int tf  = tid >> 4;
    const int tu  = tid & 15;

    {
        const float4* gA = (const float4*)(feat + ((size_t)b * Fdim + f0) * Edim);
        #pragma unroll
        for (int it = 0; it < 16; ++it) {
            const int i = tid + it * 256;
            const int f = i >> 6;
            const int qq = i & 63;
            const float4 v = gA[i];
            *(float4*)&sA[f * LDR + 4 * qq] = v;
        }
    }

    float sacc[4] = {0.f, 0.f, 0.f, 0.f};
    const float* cbb = cb + (size_t)b * Udim;

    for (int uc = 0; uc < Udim; uc += TUt) {
        __syncthreads();
        #pragma unroll
        for (int it = 0; it < 16; ++it) {
            const int i = tid + it * 256;
            const int e = i >> 4;
            const int qq = i & 15;
            const float4 v = *(const float4*)(W1 + (size_t)e * Udim + uc + 4 * qq);
            sW[(4 * qq + 0) * LDR + e] = v.x;
            sW[(4 * qq + 1) * LDR + e] = v.y;
            sW[(4 * qq + 2) * LDR + e] = v.z;
            sW[(4 * qq + 3) * LDR + e] = v.w;
        }
        __syncthreads();

        float acc[4][4] = {};
        #pragma unroll 4
        for (int e = 0; e < Edim; e += 4) {
            float4 a0 = *(const float4*)&sA[(tf +  0) * LDR + e];
            float4 a1 = *(const float4*)&sA[(tf + 16) * LDR + e];
            float4 a2 = *(const float4*)&sA[(tf + 32) * LDR + e];
            float4 a3 = *(const float4*)&sA[(tf + 48) * LDR + e];
            float4 w0 = *(const float4*)&sW[(tu +  0) * LDR + e];
            float4 w1 = *(const float4*)&sW[(tu + 16) * LDR + e];
            float4 w2 = *(const float4*)&sW[(tu + 32) * LDR + e];
            float4 w3 = *(const float4*)&sW[(tu + 48) * LDR + e];
            #define FMA4(i, j, A, W)                         \
                acc[i][j] = fmaf(A.x, W.x, acc[i][j]);       \
                acc[i][j] = fmaf(A.y, W.y, acc[i][j]);       \
                acc[i][j] = fmaf(A.z, W.z, acc[i][j]);       \
                acc[i][j] = fmaf(A.w, W.w, acc[i][j]);
            FMA4(0,0,a0,w0) FMA4(0,1,a0,w1) FMA4(0,2,a0,w2) FMA4(0,3,a0,w3)
            FMA4(1,0,a1,w0) FMA4(1,1,a1,w1) FMA4(1,2,a1,w2) FMA4(1,3,a1,w3)
            FMA4(2,0,a2,w0) FMA4(2,1,a2,w1) FMA4(2,2,a2,w2) FMA4(2,3,a2,w3)
            FMA4(3,0,a3,w0) FMA4(3,1,a3,w1) FMA4(3,2,a3,w2) FMA4(3,3,a3,w3)
            #undef FMA4
        }

        #pragma unroll
        for (int j = 0; j < 4; ++j) {
            const int u = uc + tu + 16 * j;
            const float vw = Vw[u];
            const float cuv = cbb[u];
            #pragma unroll
            for (int i = 0; i < 4; ++i)
                sacc[i] = fmaf(tanhf(acc[i][j] + cuv), vw, sacc[i]);
        }
    }

    const float vb = Vb[0];
    #pragma unroll
    for (int i = 0; i < 4; ++i) {
        float s = sacc[i];
        s += __shfl_xor(s, 1);
        s += __shfl_xor(s, 2);
        s += __shfl_xor(s, 4);
        s += __shfl_xor(s, 8);
        if (tu == 0)
            scores[(size_t)b * Fdim + f0 + tf + 16 * i] = s + vb;
    }
}

__global__ __launch_bounds__(256) void softmax_kernel(float* __restrict__ sc)
{
    __shared__ float red[256];
    const int b = blockIdx.x;
    const int tid = threadIdx.x;
    float* row = sc + (size_t)b * Fdim;

    float v[16];
    float m = -INFINITY;
    #pragma unroll
    for (int i = 0; i < 16; ++i) {
        v[i] = row[tid + 256 * i];
        m = fmaxf(m, v[i]);
    }
    red[tid] = m;
    __syncthreads();
    for (int s = 128; s > 0; s >>= 1) {
        if (tid < s) red[tid] = fmaxf(red[tid], red[tid + s]);
        __syncthreads();
    }
    m = red[0];
    __syncthreads();

    float sum = 0.f;
    #pragma unroll
    for (int i = 0; i < 16; ++i) {
        v[i] = expf(v[i] - m);
        sum += v[i];
    }
    red[tid] = sum;
    __syncthreads();
    for (int s = 128; s > 0; s >>= 1) {
        if (tid < s) red[tid] += red[tid + s];
        __syncthreads();
    }
    const float inv = 1.f / red[0];
    #pragma unroll
    for (int i = 0; i < 16; ++i)
        row[tid + 256 * i] = v[i] * inv;
}

__global__ __launch_bounds__(256) void context_kernel(
    const float* __restrict__ feat, const float* __restrict__ wts,
    float* __restrict__ ctx)
{
    const int b  = blockIdx.y;
    const int fc = blockIdx.x;
    const int e  = threadIdx.x;

    const float* fp = feat + ((size_t)b * Fdim + (size_t)fc * 256) * Edim + e;
    const float* wp = wts + (size_t)b * Fdim + (size_t)fc * 256;

    float acc = 0.f;
    #pragma unroll 8
    for (int f = 0; f < 256; ++f)
        acc = fmaf(wp[f], fp[(size_t)f * Edim], acc);

    atomicAdd(&ctx[(size_t)b * Edim + e], acc);
}

// ---------------------------------------------------------------------------
extern "C" void kernel_launch(void* const* d_in, const int* in_sizes, int n_in,
                              void* d_out, int out_size, void* d_ws, size_t ws_size,
                              hipStream_t stream)
{
    const float* features = (const float*)d_in[0];
    const float* hidden   = (const float*)d_in[1];
    const float* W1w      = (const float*)d_in[2];
    const float* W1b      = (const float*)d_in[3];
    const float* W2w      = (const float*)d_in[4];
    const float* W2b      = (const float*)d_in[5];
    const float* Vw       = (const float*)d_in[6];
    const float* Vb       = (const float*)d_in[7];

    float* ctx = (float*)d_out;                       // (B,E)
    float* wts = (float*)d_out + (size_t)Bdim * Edim; // (B,F)

    // Workspace layout:
    //   cb 128K | W1Ts 256K | scr 1M | pm 16K | ps 16K | pc 4M (64b x 64c x 256e)
    float*          cb   = (float*)d_ws;
    unsigned short* W1Ts = (unsigned short*)((char*)d_ws + 131072);
    float*          scr  = (float*)((char*)d_ws + 393216);
    float*          pm   = (float*)((char*)d_ws + 1441792);
    float*          ps   = (float*)((char*)d_ws + 1458176);
    float*          pc   = (float*)((char*)d_ws + 1474560);
    const size_t NEED = 1474560 + (size_t)Bdim * 64 * Edim * sizeof(float);
    const int mfma_ok = (ws_size >= NEED) ? 1 : 0;

    // prep: proj_h (128) + W1 transpose (32) + ctx zero (16) in one dispatch
    prep_kernel<<<176, 256, 0, stream>>>(hidden, W2w, W1b, W2b, cb,
                                         W1w, W1Ts, ctx, mfma_ok);

    if (mfma_ok) {
        dim3 sgrid(Fdim / 64, Bdim);        // (64, 64), 128-thread blocks
        score_mfma4_kernel<<<sgrid, 128, 0, stream>>>(features, W1Ts, Vw, Vb, cb,
                                                      scr, pm, ps, pc);
        merge_kernel<<<Bdim, 256, 0, stream>>>(scr, pm, ps, pc, wts, ctx);
    } else {
        dim3 sgrid(Fdim / TFt, Bdim);
        score_kernel<<<sgrid, 256, 0, stream>>>(features, W1w, Vw, Vb, cb, wts);
        softmax_kernel<<<Bdim, 256, 0, stream>>>(wts);
        dim3 cgrid(16, Bdim);
        context_kernel<<<cgrid, 256, 0, stream>>>(features, wts, ctx);
    }
}